// Round 3
// baseline (3078.585 us; speedup 1.0000x reference)
//
#include <hip/hip_runtime.h>

#define V_N 65536
#define E_N 196608

typedef unsigned short u16;

__device__ __forceinline__ float bf2f(u16 u) { return __uint_as_float(((unsigned)u) << 16); }
__device__ __forceinline__ u16 f2bf(float f) {
    unsigned x = __float_as_uint(f);
    return (u16)((x + 0x7fffu + ((x >> 16) & 1u)) >> 16);
}

// ---- edge dtype detect: int64 layout iff all 64-bit interpretations < V
__global__ void detect_kernel(const unsigned long long* e64, int* eflag) {
    __shared__ int bad;
    if (threadIdx.x == 0) bad = 0;
    __syncthreads();
    if (e64[threadIdx.x] >= (unsigned long long)V_N) atomicOr(&bad, 1);
    __syncthreads();
    if (threadIdx.x == 0) eflag[0] = bad ? 0 : 1;
}

__global__ __launch_bounds__(256) void convert_edges(const void* eraw, const int* eflag, int* eidx) {
    int k = blockIdx.x * 256 + threadIdx.x;  // 0..2E-1
    int v;
    if (eflag[0]) v = (int)((const long long*)eraw)[k];
    else          v = ((const int*)eraw)[k];
    eidx[k] = v;
}

// ---- CSR build
__global__ __launch_bounds__(256) void cnt_kernel(const int* __restrict__ eidx, int* __restrict__ cnt) {
    int e = blockIdx.x * 256 + threadIdx.x;
    atomicAdd(&cnt[eidx[2 * e]], 1);
    atomicAdd(&cnt[eidx[2 * e + 1]], 1);
}

__global__ void scan_kernel(const int* __restrict__ cnt, int* __restrict__ off, int* __restrict__ cursor) {
    __shared__ int partial[1024];
    int t = threadIdx.x;
    int base = t * 64;
    int s = 0;
    #pragma unroll 4
    for (int k = 0; k < 64; ++k) s += cnt[base + k];
    partial[t] = s;
    __syncthreads();
    for (int d = 1; d < 1024; d <<= 1) {
        int v = (t >= d) ? partial[t - d] : 0;
        __syncthreads();
        partial[t] += v;
        __syncthreads();
    }
    int run = (t == 0) ? 0 : partial[t - 1];
    for (int k = 0; k < 64; ++k) {
        int idx = base + k;
        off[idx] = run; cursor[idx] = run;
        run += cnt[idx];
    }
    if (t == 1023) off[V_N] = run;
}

__global__ __launch_bounds__(256) void fill_adj(const int* __restrict__ eidx, int* __restrict__ cursor,
                                                int* __restrict__ adj) {
    int e = blockIdx.x * 256 + threadIdx.x;
    int i = eidx[2 * e], j = eidx[2 * e + 1];
    adj[atomicAdd(&cursor[i], 1)] = j;
    adj[atomicAdd(&cursor[j], 1)] = i;
}

// ---- layer-0 gather (din=3, fp32): thread per vertex
__global__ __launch_bounds__(256) void gather0(const int* __restrict__ off, const int* __restrict__ adj,
                                               const float* __restrict__ verts, float* __restrict__ S0) {
    int i = blockIdx.x * 256 + threadIdx.x;
    float s0 = 0.f, s1 = 0.f, s2 = 0.f;
    int o1 = off[i + 1];
    for (int o = off[i]; o < o1; ++o) {
        int j = adj[o];
        s0 += verts[3 * j]; s1 += verts[3 * j + 1]; s2 += verts[3 * j + 2];
    }
    S0[3 * i] = s0; S0[3 * i + 1] = s1; S0[3 * i + 2] = s2;
}

// ---- layer 0 dense (din=3 -> dout=256), bf16 out
__global__ __launch_bounds__(256) void l0_compute(
    const float* __restrict__ verts, const float* __restrict__ S0, const int* __restrict__ off,
    const float* __restrict__ w0, const float* __restrict__ b0,
    const float* __restrict__ w1, const float* __restrict__ b1, u16* __restrict__ Y) {
    int gid = blockIdx.x * 256 + threadIdx.x;
    int r = gid >> 6;
    int c = (gid & 63) << 2;
    float x0 = verts[3 * r], x1 = verts[3 * r + 1], x2 = verts[3 * r + 2];
    float s0 = S0[3 * r], s1 = S0[3 * r + 1], s2 = S0[3 * r + 2];
    float d = (float)(off[r + 1] - off[r]);
    float4 A0 = *(const float4*)&w0[c], A1 = *(const float4*)&w0[256 + c], A2 = *(const float4*)&w0[512 + c];
    float4 C0 = *(const float4*)&w1[c], C1 = *(const float4*)&w1[256 + c], C2 = *(const float4*)&w1[512 + c];
    float4 B0 = *(const float4*)&b0[c], B1 = *(const float4*)&b1[c];
    float4 y;
    y.x = B0.x + d * B1.x + x0 * A0.x + x1 * A1.x + x2 * A2.x + s0 * C0.x + s1 * C1.x + s2 * C2.x;
    y.y = B0.y + d * B1.y + x0 * A0.y + x1 * A1.y + x2 * A2.y + s0 * C0.y + s1 * C1.y + s2 * C2.y;
    y.z = B0.z + d * B1.z + x0 * A0.z + x1 * A1.z + x2 * A2.z + s0 * C0.z + s1 * C1.z + s2 * C2.z;
    y.w = B0.w + d * B1.w + x0 * A0.w + x1 * A1.w + x2 * A2.w + s0 * C0.w + s1 * C1.w + s2 * C2.w;
    ushort4 o; o.x = f2bf(y.x); o.y = f2bf(y.y); o.z = f2bf(y.z); o.w = f2bf(y.w);
    *(ushort4*)&Y[(size_t)r * 256 + c] = o;
}

// ---- neighbor gather, bf16 in -> bf16 out (fp32 accum): block per vertex
__global__ __launch_bounds__(256) void gather_kernel(
    const int* __restrict__ off, const int* __restrict__ adj,
    const u16* __restrict__ X, u16* __restrict__ S, int K) {
    int i = blockIdx.x;
    int o0 = off[i], o1 = off[i + 1];
    for (int c = threadIdx.x; c < K; c += 256) {
        float s = 0.f;
        for (int o = o0; o < o1; ++o)
            s += bf2f(X[(size_t)adj[o] * K + c]);
        S[(size_t)i * K + c] = f2bf(s);
    }
}

// ---- fused GEMM: Y[:,cb:cb+ldY] = X@w0[:,cb..] + S@w1[:,cb..] + b0 + deg*b1 (bf16 out)
__global__ __launch_bounds__(256) void gemm_fused(
    const u16* __restrict__ X, const u16* __restrict__ S, const int* __restrict__ off,
    const float* __restrict__ w0, const float* __restrict__ b0,
    const float* __restrict__ w1, const float* __restrict__ b1,
    u16* __restrict__ Y, int Nw, int K, int colbase, int ldY) {
    __shared__ float As[16][68];
    __shared__ float Bs[16][64];
    int tid = threadIdx.x;
    int tx = tid & 15, ty = tid >> 4;
    int brow = blockIdx.y * 64, bcol = blockIdx.x * 64;
    int ar = tid >> 2, ak = (tid & 3) << 2;
    int bk = tid >> 4, bc = (tid & 15) << 2;
    float acc[4][4] = {};

    for (int ph = 0; ph < 2; ++ph) {
        const u16* Ap = ph ? S : X;
        const float* Bw = ph ? w1 : w0;
        for (int k0 = 0; k0 < K; k0 += 16) {
            ushort4 a = *(const ushort4*)&Ap[(size_t)(brow + ar) * K + k0 + ak];
            As[ak + 0][ar] = bf2f(a.x); As[ak + 1][ar] = bf2f(a.y);
            As[ak + 2][ar] = bf2f(a.z); As[ak + 3][ar] = bf2f(a.w);
            *(float4*)&Bs[bk][bc] = *(const float4*)&Bw[(size_t)(k0 + bk) * Nw + colbase + bcol + bc];
            __syncthreads();
            #pragma unroll
            for (int k = 0; k < 16; ++k) {
                float4 av = *(const float4*)&As[k][ty << 2];
                float4 bv = *(const float4*)&Bs[k][tx << 2];
                float a_[4] = {av.x, av.y, av.z, av.w};
                float b_[4] = {bv.x, bv.y, bv.z, bv.w};
                #pragma unroll
                for (int i = 0; i < 4; ++i)
                    #pragma unroll
                    for (int j = 0; j < 4; ++j)
                        acc[i][j] += a_[i] * b_[j];
            }
            __syncthreads();
        }
    }
    float4 B0 = *(const float4*)&b0[colbase + bcol + (tx << 2)];
    float4 B1 = *(const float4*)&b1[colbase + bcol + (tx << 2)];
    #pragma unroll
    for (int i = 0; i < 4; ++i) {
        int row = brow + (ty << 2) + i;
        float d = (float)(off[row + 1] - off[row]);
        ushort4 o;
        o.x = f2bf(acc[i][0] + B0.x + d * B1.x);
        o.y = f2bf(acc[i][1] + B0.y + d * B1.y);
        o.z = f2bf(acc[i][2] + B0.z + d * B1.z);
        o.w = f2bf(acc[i][3] + B0.w + d * B1.w);
        *(ushort4*)&Y[(size_t)row * ldY + bcol + (tx << 2)] = o;
    }
}

// ---- per-channel sum / sumsq
__global__ __launch_bounds__(256) void bn_stats(
    const u16* __restrict__ Y, float* __restrict__ sums, float* __restrict__ sqs, int N) {
    int c = blockIdx.y * 256 + threadIdx.x;
    int r0 = blockIdx.x * 256;
    float s = 0.f, q = 0.f;
    for (int r = r0; r < r0 + 256; ++r) {
        float v = bf2f(Y[(size_t)r * N + c]);
        s += v; q += v * v;
    }
    atomicAdd(&sums[c], s);
    atomicAdd(&sqs[c], q);
}

__global__ void bn_finalize(const float* __restrict__ sums, const float* __restrict__ sqs,
                            const float* __restrict__ g, const float* __restrict__ be,
                            float* __restrict__ scale, float* __restrict__ shift) {
    int c = blockIdx.x * 256 + threadIdx.x;
    float mu = sums[c] * (1.f / V_N);
    float var = sqs[c] * (1.f / V_N) - mu * mu;
    float sc = g[c] * rsqrtf(var + 1e-5f);
    scale[c] = sc;
    shift[c] = be[c] - mu * sc;
}

__global__ __launch_bounds__(256) void bn_apply(
    u16* __restrict__ Y, const float* __restrict__ scale, const float* __restrict__ shift, int Nmask) {
    int gid = blockIdx.x * 256 + threadIdx.x;
    int c = (gid << 2) & Nmask;
    ushort4 v = *(ushort4*)&Y[(size_t)gid * 4];
    float4 sc = *(const float4*)&scale[c];
    float4 sh = *(const float4*)&shift[c];
    ushort4 o;
    o.x = f2bf(fmaxf(bf2f(v.x) * sc.x + sh.x, 0.f));
    o.y = f2bf(fmaxf(bf2f(v.y) * sc.y + sh.y, 0.f));
    o.z = f2bf(fmaxf(bf2f(v.z) * sc.z + sh.z, 0.f));
    o.w = f2bf(fmaxf(bf2f(v.w) * sc.w + sh.w, 0.f));
    *(ushort4*)&Y[(size_t)gid * 4] = o;
}

// ---- segment-mean pool over compact chunk (ld columns), contiguous 1024-row segments
__global__ __launch_bounds__(256) void pool_kernel(const u16* __restrict__ X, float* __restrict__ pooled,
                                                   int ld, int colbase) {
    int m = blockIdx.x;
    int c = blockIdx.y * 256 + threadIdx.x;
    float s = 0.f;
    const u16* p = X + (size_t)m * 1024 * ld + c;
    for (int r = 0; r < 1024; ++r) s += bf2f(p[(size_t)r * ld]);
    pooled[m * 1024 + colbase + c] = s * (1.f / 1024.f);
}

// ---- fc1 + relu + 4 heads
__global__ __launch_bounds__(128) void head_kernel(
    const float* __restrict__ pooled,
    const float* __restrict__ fc1w, const float* __restrict__ fc1b,
    const float* __restrict__ sw, const float* __restrict__ sb,
    const float* __restrict__ mw, const float* __restrict__ mb,
    const float* __restrict__ fw, const float* __restrict__ fb,
    const float* __restrict__ aw, const float* __restrict__ ab,
    float* __restrict__ out) {
    __shared__ float xs[1024];
    __shared__ float hs[128];
    int m = blockIdx.x, t = threadIdx.x;
    for (int k = t; k < 1024; k += 128) xs[k] = pooled[m * 1024 + k];
    __syncthreads();
    float acc = fc1b[t];
    for (int k = 0; k < 1024; ++k) acc += xs[k] * fc1w[k * 128 + t];
    hs[t] = fmaxf(acc, 0.f);
    __syncthreads();
    if (t < 14) {
        const float* w; const float* bv; int cdim; int o; int base;
        if (t < 3)      { w = sw; bv = sb; cdim = 3; o = t;     base = 0;   }
        else if (t < 5) { w = mw; bv = mb; cdim = 2; o = t - 3; base = 192; }
        else if (t < 9) { w = fw; bv = fb; cdim = 4; o = t - 5; base = 320; }
        else            { w = aw; bv = ab; cdim = 5; o = t - 9; base = 576; }
        float a = bv[o];
        for (int k = 0; k < 128; ++k) a += hs[k] * w[k * cdim + o];
        out[base + m * cdim + o] = a;
    }
}

extern "C" void kernel_launch(void* const* d_in, const int* in_sizes, int n_in,
                              void* d_out, int out_size, void* d_ws, size_t ws_size,
                              hipStream_t stream)
{
    const float* verts = (const float*)d_in[0];
    const void*  eraw  = d_in[1];
    const float* w0_0 = (const float*)d_in[3];  const float* b0_0 = (const float*)d_in[4];
    const float* w1_0 = (const float*)d_in[5];  const float* b1_0 = (const float*)d_in[6];
    const float* g_0  = (const float*)d_in[7];  const float* be_0 = (const float*)d_in[8];
    const float* w0_1 = (const float*)d_in[9];  const float* b0_1 = (const float*)d_in[10];
    const float* w1_1 = (const float*)d_in[11]; const float* b1_1 = (const float*)d_in[12];
    const float* g_1  = (const float*)d_in[13]; const float* be_1 = (const float*)d_in[14];
    const float* w0_2 = (const float*)d_in[15]; const float* b0_2 = (const float*)d_in[16];
    const float* w1_2 = (const float*)d_in[17]; const float* b1_2 = (const float*)d_in[18];
    const float* g_2  = (const float*)d_in[19]; const float* be_2 = (const float*)d_in[20];
    const float* fc1w = (const float*)d_in[21]; const float* fc1b = (const float*)d_in[22];
    const float* sw = (const float*)d_in[23]; const float* sb = (const float*)d_in[24];
    const float* mw = (const float*)d_in[25]; const float* mb = (const float*)d_in[26];
    const float* fw = (const float*)d_in[27]; const float* fb = (const float*)d_in[28];
    const float* aw = (const float*)d_in[29]; const float* ab = (const float*)d_in[30];
    float* out = (float*)d_out;

    const size_t V = V_N, E = E_N;

    // ---- workspace layout (byte cursor, 256B aligned blocks)
    char* p = (char*)d_ws;
    auto alloc = [&](size_t bytes) { void* r = (void*)p; p += (bytes + 255) & ~(size_t)255; return r; };
    int*   eidx   = (int*)  alloc(2 * E * 4);
    int*   eflag  = (int*)  alloc(64);
    int*   cnt    = (int*)  alloc(V * 4);
    int*   off    = (int*)  alloc((V + 1) * 4);
    int*   cursor = (int*)  alloc(V * 4);
    int*   adj    = (int*)  alloc(2 * E * 4);
    float* S0     = (float*)alloc(V * 3 * 4);
    float* stats  = (float*)alloc(2048 * 4);
    float* scalev = (float*)alloc(1024 * 4);
    float* shiftv = (float*)alloc(1024 * 4);
    float* pooled = (float*)alloc(65536 * 4);
    u16*   X1     = (u16*)  alloc(V * 256 * 2);   // layer-0 out; aliased as Y2c in L2
    u16*   X2     = (u16*)  alloc(V * 512 * 2);   // layer-1 out
    u16*   S      = (u16*)  alloc(V * 512 * 2);   // gathered neighbor sums (bf16)
    u16*   Y2c    = X1;                            // alias: X1 dead once L2 starts
    size_t needed = (size_t)(p - (char*)d_ws);

    if (ws_size < needed) {
        // Workspace too small: do nothing but zero the output (deterministic,
        // graph-safe). Bench will show absmax=3.06e-2 instead of a crash.
        hipMemsetAsync(d_out, 0, (size_t)out_size * 4, stream);
        return;
    }

    // ---- edges -> int32, CSR
    detect_kernel<<<1, 256, 0, stream>>>((const unsigned long long*)eraw, eflag);
    convert_edges<<<2 * E / 256, 256, 0, stream>>>(eraw, eflag, eidx);
    hipMemsetAsync(cnt, 0, V * 4, stream);
    cnt_kernel<<<E / 256, 256, 0, stream>>>(eidx, cnt);
    scan_kernel<<<1, 1024, 0, stream>>>(cnt, off, cursor);
    fill_adj<<<E / 256, 256, 0, stream>>>(eidx, cursor, adj);

    // ---- layer 0 (3 -> 256)
    gather0<<<V / 256, 256, 0, stream>>>(off, adj, verts, S0);
    l0_compute<<<V * 64 / 256, 256, 0, stream>>>(verts, S0, off, w0_0, b0_0, w1_0, b1_0, X1);
    hipMemsetAsync(stats, 0, 2048 * 4, stream);
    bn_stats<<<dim3(V / 256, 1), 256, 0, stream>>>(X1, stats, stats + 1024, 256);
    bn_finalize<<<1, 256, 0, stream>>>(stats, stats + 1024, g_0, be_0, scalev, shiftv);
    bn_apply<<<V * 256 / 4 / 256, 256, 0, stream>>>(X1, scalev, shiftv, 255);

    // ---- layer 1 (256 -> 512)
    gather_kernel<<<V, 256, 0, stream>>>(off, adj, X1, S, 256);
    gemm_fused<<<dim3(8, V / 64), 256, 0, stream>>>(X1, S, off, w0_1, b0_1, w1_1, b1_1, X2, 512, 256, 0, 512);
    hipMemsetAsync(stats, 0, 2048 * 4, stream);
    bn_stats<<<dim3(V / 256, 2), 256, 0, stream>>>(X2, stats, stats + 1024, 512);
    bn_finalize<<<2, 256, 0, stream>>>(stats, stats + 1024, g_1, be_1, scalev, shiftv);
    bn_apply<<<V * 512 / 4 / 256, 256, 0, stream>>>(X2, scalev, shiftv, 511);

    // ---- layer 2 (512 -> 1024), output processed in 4 column chunks of 256
    gather_kernel<<<V, 256, 0, stream>>>(off, adj, X2, S, 512);
    for (int cb = 0; cb < 1024; cb += 256) {
        gemm_fused<<<dim3(4, V / 64), 256, 0, stream>>>(X2, S, off, w0_2, b0_2, w1_2, b1_2,
                                                        Y2c, 1024, 512, cb, 256);
        hipMemsetAsync(stats, 0, 2048 * 4, stream);
        bn_stats<<<dim3(V / 256, 1), 256, 0, stream>>>(Y2c, stats, stats + 1024, 256);
        bn_finalize<<<1, 256, 0, stream>>>(stats, stats + 1024, g_2 + cb, be_2 + cb, scalev, shiftv);
        bn_apply<<<V * 256 / 4 / 256, 256, 0, stream>>>(Y2c, scalev, shiftv, 255);
        pool_kernel<<<dim3(64, 1), 256, 0, stream>>>(Y2c, pooled, 256, cb);
    }

    // ---- pool + heads
    head_kernel<<<64, 128, 0, stream>>>(pooled, fc1w, fc1b, sw, sb, mw, mb, fw, fb, aw, ab, out);
}

// Round 4
// 1362.829 us; speedup vs baseline: 2.2590x; 2.2590x over previous
//
#include <hip/hip_runtime.h>

#define V_N 65536
#define E_N 196608

typedef unsigned short u16;
typedef __attribute__((ext_vector_type(8))) short bf16x8;
typedef __attribute__((ext_vector_type(4))) float f32x4;

__device__ __forceinline__ float bf2f(u16 u) { return __uint_as_float(((unsigned)u) << 16); }
__device__ __forceinline__ u16 f2bf(float f) {
    unsigned x = __float_as_uint(f);
    return (u16)((x + 0x7fffu + ((x >> 16) & 1u)) >> 16);
}

__device__ __forceinline__ void gload_lds16(const u16* g, u16* l) {
    __builtin_amdgcn_global_load_lds(
        (const __attribute__((address_space(1))) unsigned int*)g,
        (__attribute__((address_space(3))) unsigned int*)l, 16, 0, 0);
}

// ---- edge dtype detect: int64 layout iff all 64-bit interpretations < V
__global__ void detect_kernel(const unsigned long long* e64, int* eflag) {
    __shared__ int bad;
    if (threadIdx.x == 0) bad = 0;
    __syncthreads();
    if (e64[threadIdx.x] >= (unsigned long long)V_N) atomicOr(&bad, 1);
    __syncthreads();
    if (threadIdx.x == 0) eflag[0] = bad ? 0 : 1;
}

__global__ __launch_bounds__(256) void convert_edges(const void* eraw, const int* eflag, int* eidx) {
    int k = blockIdx.x * 256 + threadIdx.x;
    int v;
    if (eflag[0]) v = (int)((const long long*)eraw)[k];
    else          v = ((const int*)eraw)[k];
    eidx[k] = v;
}

// ---- CSR build
__global__ __launch_bounds__(256) void cnt_kernel(const int* __restrict__ eidx, int* __restrict__ cnt) {
    int e = blockIdx.x * 256 + threadIdx.x;
    atomicAdd(&cnt[eidx[2 * e]], 1);
    atomicAdd(&cnt[eidx[2 * e + 1]], 1);
}

__global__ void scan_kernel(const int* __restrict__ cnt, int* __restrict__ off, int* __restrict__ cursor) {
    __shared__ int partial[1024];
    int t = threadIdx.x;
    int base = t * 64;
    int s = 0;
    #pragma unroll 4
    for (int k = 0; k < 64; ++k) s += cnt[base + k];
    partial[t] = s;
    __syncthreads();
    for (int d = 1; d < 1024; d <<= 1) {
        int v = (t >= d) ? partial[t - d] : 0;
        __syncthreads();
        partial[t] += v;
        __syncthreads();
    }
    int run = (t == 0) ? 0 : partial[t - 1];
    for (int k = 0; k < 64; ++k) {
        int idx = base + k;
        off[idx] = run; cursor[idx] = run;
        run += cnt[idx];
    }
    if (t == 1023) off[V_N] = run;
}

__global__ __launch_bounds__(256) void fill_adj(const int* __restrict__ eidx, int* __restrict__ cursor,
                                                int* __restrict__ adj) {
    int e = blockIdx.x * 256 + threadIdx.x;
    int i = eidx[2 * e], j = eidx[2 * e + 1];
    adj[atomicAdd(&cursor[i], 1)] = j;
    adj[atomicAdd(&cursor[j], 1)] = i;
}

__global__ __launch_bounds__(256) void degf_kernel(const int* __restrict__ off, float* __restrict__ deg) {
    int i = blockIdx.x * 256 + threadIdx.x;
    deg[i] = (float)(off[i + 1] - off[i]);
}

// ---- weight convert+transpose: w [K][N] fp32 -> wt [N][K] bf16
__global__ __launch_bounds__(256) void wtrans(const float* __restrict__ w, u16* __restrict__ wt,
                                              int K, int N) {
    int gid = blockIdx.x * 256 + threadIdx.x;
    if (gid >= N * K) return;
    int n = gid / K, k = gid % K;
    wt[gid] = f2bf(w[(size_t)k * N + n]);
}

// ---- layer-0 gather (din=3, fp32)
__global__ __launch_bounds__(256) void gather0(const int* __restrict__ off, const int* __restrict__ adj,
                                               const float* __restrict__ verts, float* __restrict__ S0) {
    int i = blockIdx.x * 256 + threadIdx.x;
    float s0 = 0.f, s1 = 0.f, s2 = 0.f;
    int o1 = off[i + 1];
    for (int o = off[i]; o < o1; ++o) {
        int j = adj[o];
        s0 += verts[3 * j]; s1 += verts[3 * j + 1]; s2 += verts[3 * j + 2];
    }
    S0[3 * i] = s0; S0[3 * i + 1] = s1; S0[3 * i + 2] = s2;
}

// ---- layer 0 dense (din=3 -> dout=256), bf16 out
__global__ __launch_bounds__(256) void l0_compute(
    const float* __restrict__ verts, const float* __restrict__ S0, const int* __restrict__ off,
    const float* __restrict__ w0, const float* __restrict__ b0,
    const float* __restrict__ w1, const float* __restrict__ b1, u16* __restrict__ Y) {
    int gid = blockIdx.x * 256 + threadIdx.x;
    int r = gid >> 6;
    int c = (gid & 63) << 2;
    float x0 = verts[3 * r], x1 = verts[3 * r + 1], x2 = verts[3 * r + 2];
    float s0 = S0[3 * r], s1 = S0[3 * r + 1], s2 = S0[3 * r + 2];
    float d = (float)(off[r + 1] - off[r]);
    float4 A0 = *(const float4*)&w0[c], A1 = *(const float4*)&w0[256 + c], A2 = *(const float4*)&w0[512 + c];
    float4 C0 = *(const float4*)&w1[c], C1 = *(const float4*)&w1[256 + c], C2 = *(const float4*)&w1[512 + c];
    float4 B0 = *(const float4*)&b0[c], B1 = *(const float4*)&b1[c];
    float4 y;
    y.x = B0.x + d * B1.x + x0 * A0.x + x1 * A1.x + x2 * A2.x + s0 * C0.x + s1 * C1.x + s2 * C2.x;
    y.y = B0.y + d * B1.y + x0 * A0.y + x1 * A1.y + x2 * A2.y + s0 * C0.y + s1 * C1.y + s2 * C2.y;
    y.z = B0.z + d * B1.z + x0 * A0.z + x1 * A1.z + x2 * A2.z + s0 * C0.z + s1 * C1.z + s2 * C2.z;
    y.w = B0.w + d * B1.w + x0 * A0.w + x1 * A1.w + x2 * A2.w + s0 * C0.w + s1 * C1.w + s2 * C2.w;
    ushort4 o; o.x = f2bf(y.x); o.y = f2bf(y.y); o.z = f2bf(y.z); o.w = f2bf(y.w);
    *(ushort4*)&Y[(size_t)r * 256 + c] = o;
}

// ---- neighbor gather, bf16 in -> bf16 out (fp32 accum): block per vertex
__global__ __launch_bounds__(256) void gather_kernel(
    const int* __restrict__ off, const int* __restrict__ adj,
    const u16* __restrict__ X, u16* __restrict__ S, int K) {
    int i = blockIdx.x;
    int o0 = off[i], o1 = off[i + 1];
    for (int c = threadIdx.x; c < K; c += 256) {
        float s = 0.f;
        for (int o = o0; o < o1; ++o)
            s += bf2f(X[(size_t)adj[o] * K + c]);
        S[(size_t)i * K + c] = f2bf(s);
    }
}

// ---- MFMA GEMM: Y[:, :128*gx] = X@W0t^T + S@W1t^T + b0 + deg*b1  (bf16 out)
// Wt is [N][K] bf16 (pre-transposed); tile 128x128, BK=64, 4 waves 2x2.
// LDS linear [row][64] with XOR swizzle (16B granule ^= row&7) on BOTH
// the pre-swizzled global source and the ds_read address (rule #21).
__global__ __launch_bounds__(256) void gemm_mfma(
    const u16* __restrict__ X, const u16* __restrict__ S,
    const u16* __restrict__ W0t, const u16* __restrict__ W1t,
    const float* __restrict__ b0, const float* __restrict__ b1,
    const float* __restrict__ deg,
    u16* __restrict__ Y, int K, int colbase, int ldY)
{
    __shared__ u16 As[128 * 64];
    __shared__ u16 Bs[128 * 64];
    const int tid = threadIdx.x;
    const int wid = tid >> 6, lane = tid & 63;
    const int brow = blockIdx.y * 128;
    const int bcol = blockIdx.x * 128;
    const int wm = wid >> 1, wn = wid & 1;

    const int sr = lane >> 3;       // staging: row within 8-row group
    const int sg = lane & 7;        // physical 16B granule
    const int sgl = sg ^ sr;        // logical granule (pre-swizzled source)
    const int fr = lane & 15;       // fragment row/col
    const int fg = lane >> 4;       // fragment k-granule

    f32x4 acc[4][4] = {};

    for (int ph = 0; ph < 2; ++ph) {
        const u16* Ap = ph ? S : X;
        const u16* Bp = (ph ? W1t : W0t) + (size_t)colbase * K;
        const u16* asrc = Ap + (size_t)(brow + wid * 32 + sr) * K + sgl * 8;
        const u16* bsrc = Bp + (size_t)(bcol + wid * 32 + sr) * K + sgl * 8;
        u16* adst = As + wid * 32 * 64;
        u16* bdst = Bs + wid * 32 * 64;

        for (int k0 = 0; k0 < K; k0 += 64) {
            if (ph | k0) __syncthreads();
            #pragma unroll
            for (int i = 0; i < 4; ++i) {
                gload_lds16(asrc + (size_t)i * 8 * K + k0, adst + i * 8 * 64);
                gload_lds16(bsrc + (size_t)i * 8 * K + k0, bdst + i * 8 * 64);
            }
            __syncthreads();

            bf16x8 afrag[4][2], bfrag[4][2];
            #pragma unroll
            for (int f = 0; f < 4; ++f) {
                int ar = wm * 64 + f * 16 + fr;
                int br = wn * 64 + f * 16 + fr;
                #pragma unroll
                for (int ks = 0; ks < 2; ++ks) {
                    int gp = (ks * 4 + fg) ^ (fr & 7);
                    afrag[f][ks] = *(const bf16x8*)(As + ar * 64 + gp * 8);
                    bfrag[f][ks] = *(const bf16x8*)(Bs + br * 64 + gp * 8);
                }
            }
            #pragma unroll
            for (int ks = 0; ks < 2; ++ks)
                #pragma unroll
                for (int fm = 0; fm < 4; ++fm)
                    #pragma unroll
                    for (int fn = 0; fn < 4; ++fn)
                        acc[fm][fn] = __builtin_amdgcn_mfma_f32_16x16x32_bf16(
                            afrag[fm][ks], bfrag[fn][ks], acc[fm][fn], 0, 0, 0);
        }
    }

    // epilogue: C/D layout col = lane&15, row = (lane>>4)*4 + reg
    #pragma unroll
    for (int fn = 0; fn < 4; ++fn) {
        int col = bcol + wn * 64 + fn * 16 + fr;
        float B0 = b0[colbase + col];
        float B1 = b1[colbase + col];
        #pragma unroll
        for (int fm = 0; fm < 4; ++fm) {
            #pragma unroll
            for (int r = 0; r < 4; ++r) {
                int row = brow + wm * 64 + fm * 16 + fg * 4 + r;
                float v = acc[fm][fn][r] + B0 + deg[row] * B1;
                Y[(size_t)row * ldY + col] = f2bf(v);
            }
        }
    }
}

// ---- per-channel sum / sumsq
__global__ __launch_bounds__(256) void bn_stats(
    const u16* __restrict__ Y, float* __restrict__ sums, float* __restrict__ sqs, int N) {
    int c = blockIdx.y * 256 + threadIdx.x;
    int r0 = blockIdx.x * 256;
    float s = 0.f, q = 0.f;
    for (int r = r0; r < r0 + 256; ++r) {
        float v = bf2f(Y[(size_t)r * N + c]);
        s += v; q += v * v;
    }
    atomicAdd(&sums[c], s);
    atomicAdd(&sqs[c], q);
}

__global__ void bn_finalize(const float* __restrict__ sums, const float* __restrict__ sqs,
                            const float* __restrict__ g, const float* __restrict__ be,
                            float* __restrict__ scale, float* __restrict__ shift) {
    int c = blockIdx.x * 256 + threadIdx.x;
    float mu = sums[c] * (1.f / V_N);
    float var = sqs[c] * (1.f / V_N) - mu * mu;
    float sc = g[c] * rsqrtf(var + 1e-5f);
    scale[c] = sc;
    shift[c] = be[c] - mu * sc;
}

__global__ __launch_bounds__(256) void bn_apply(
    u16* __restrict__ Y, const float* __restrict__ scale, const float* __restrict__ shift, int Nmask) {
    int gid = blockIdx.x * 256 + threadIdx.x;
    int c = (gid << 2) & Nmask;
    ushort4 v = *(ushort4*)&Y[(size_t)gid * 4];
    float4 sc = *(const float4*)&scale[c];
    float4 sh = *(const float4*)&shift[c];
    ushort4 o;
    o.x = f2bf(fmaxf(bf2f(v.x) * sc.x + sh.x, 0.f));
    o.y = f2bf(fmaxf(bf2f(v.y) * sc.y + sh.y, 0.f));
    o.z = f2bf(fmaxf(bf2f(v.z) * sc.z + sh.z, 0.f));
    o.w = f2bf(fmaxf(bf2f(v.w) * sc.w + sh.w, 0.f));
    *(ushort4*)&Y[(size_t)gid * 4] = o;
}

// ---- segment-mean pool over compact chunk (ld columns), contiguous 1024-row segments
__global__ __launch_bounds__(256) void pool_kernel(const u16* __restrict__ X, float* __restrict__ pooled,
                                                   int ld, int colbase) {
    int m = blockIdx.x;
    int c = blockIdx.y * 256 + threadIdx.x;
    float s = 0.f;
    const u16* p = X + (size_t)m * 1024 * ld + c;
    for (int r = 0; r < 1024; ++r) s += bf2f(p[(size_t)r * ld]);
    pooled[m * 1024 + colbase + c] = s * (1.f / 1024.f);
}

// ---- fc1 + relu + 4 heads
__global__ __launch_bounds__(128) void head_kernel(
    const float* __restrict__ pooled,
    const float* __restrict__ fc1w, const float* __restrict__ fc1b,
    const float* __restrict__ sw, const float* __restrict__ sb,
    const float* __restrict__ mw, const float* __restrict__ mb,
    const float* __restrict__ fw, const float* __restrict__ fb,
    const float* __restrict__ aw, const float* __restrict__ ab,
    float* __restrict__ out) {
    __shared__ float xs[1024];
    __shared__ float hs[128];
    int m = blockIdx.x, t = threadIdx.x;
    for (int k = t; k < 1024; k += 128) xs[k] = pooled[m * 1024 + k];
    __syncthreads();
    float acc = fc1b[t];
    for (int k = 0; k < 1024; ++k) acc += xs[k] * fc1w[k * 128 + t];
    hs[t] = fmaxf(acc, 0.f);
    __syncthreads();
    if (t < 14) {
        const float* w; const float* bv; int cdim; int o; int base;
        if (t < 3)      { w = sw; bv = sb; cdim = 3; o = t;     base = 0;   }
        else if (t < 5) { w = mw; bv = mb; cdim = 2; o = t - 3; base = 192; }
        else if (t < 9) { w = fw; bv = fb; cdim = 4; o = t - 5; base = 320; }
        else            { w = aw; bv = ab; cdim = 5; o = t - 9; base = 576; }
        float a = bv[o];
        for (int k = 0; k < 128; ++k) a += hs[k] * w[k * cdim + o];
        out[base + m * cdim + o] = a;
    }
}

extern "C" void kernel_launch(void* const* d_in, const int* in_sizes, int n_in,
                              void* d_out, int out_size, void* d_ws, size_t ws_size,
                              hipStream_t stream)
{
    const float* verts = (const float*)d_in[0];
    const void*  eraw  = d_in[1];
    const float* w0_0 = (const float*)d_in[3];  const float* b0_0 = (const float*)d_in[4];
    const float* w1_0 = (const float*)d_in[5];  const float* b1_0 = (const float*)d_in[6];
    const float* g_0  = (const float*)d_in[7];  const float* be_0 = (const float*)d_in[8];
    const float* w0_1 = (const float*)d_in[9];  const float* b0_1 = (const float*)d_in[10];
    const float* w1_1 = (const float*)d_in[11]; const float* b1_1 = (const float*)d_in[12];
    const float* g_1  = (const float*)d_in[13]; const float* be_1 = (const float*)d_in[14];
    const float* w0_2 = (const float*)d_in[15]; const float* b0_2 = (const float*)d_in[16];
    const float* w1_2 = (const float*)d_in[17]; const float* b1_2 = (const float*)d_in[18];
    const float* g_2  = (const float*)d_in[19]; const float* be_2 = (const float*)d_in[20];
    const float* fc1w = (const float*)d_in[21]; const float* fc1b = (const float*)d_in[22];
    const float* sw = (const float*)d_in[23]; const float* sb = (const float*)d_in[24];
    const float* mw = (const float*)d_in[25]; const float* mb = (const float*)d_in[26];
    const float* fw = (const float*)d_in[27]; const float* fb = (const float*)d_in[28];
    const float* aw = (const float*)d_in[29]; const float* ab = (const float*)d_in[30];
    float* out = (float*)d_out;

    const size_t V = V_N, E = E_N;

    // ---- workspace layout
    char* p = (char*)d_ws;
    auto alloc = [&](size_t bytes) { void* r = (void*)p; p += (bytes + 255) & ~(size_t)255; return r; };
    int*   eidx   = (int*)  alloc(2 * E * 4);
    int*   eflag  = (int*)  alloc(64);
    int*   cnt    = (int*)  alloc(V * 4);
    int*   off    = (int*)  alloc((V + 1) * 4);
    int*   cursor = (int*)  alloc(V * 4);
    int*   adj    = (int*)  alloc(2 * E * 4);
    float* degf   = (float*)alloc(V * 4);
    float* S0     = (float*)alloc(V * 3 * 4);
    float* stats  = (float*)alloc(2048 * 4);
    float* scalev = (float*)alloc(1024 * 4);
    float* shiftv = (float*)alloc(1024 * 4);
    float* pooled = (float*)alloc(65536 * 4);
    u16*   w01t   = (u16*)  alloc(512 * 256 * 2);    // [N=512][K=256]
    u16*   w11t   = (u16*)  alloc(512 * 256 * 2);
    u16*   w02t   = (u16*)  alloc(1024 * 512 * 2);   // [N=1024][K=512]
    u16*   w12t   = (u16*)  alloc(1024 * 512 * 2);
    u16*   X1     = (u16*)  alloc(V * 256 * 2);      // layer-0 out; aliased Y2c in L2
    u16*   X2     = (u16*)  alloc(V * 512 * 2);      // layer-1 out
    u16*   S      = (u16*)  alloc(V * 512 * 2);      // gathered neighbor sums
    u16*   Y2c    = X1;
    size_t needed = (size_t)(p - (char*)d_ws);

    if (ws_size < needed) {
        hipMemsetAsync(d_out, 0, (size_t)out_size * 4, stream);
        return;
    }

    // ---- edges -> int32, CSR, deg
    detect_kernel<<<1, 256, 0, stream>>>((const unsigned long long*)eraw, eflag);
    convert_edges<<<2 * E / 256, 256, 0, stream>>>(eraw, eflag, eidx);
    hipMemsetAsync(cnt, 0, V * 4, stream);
    cnt_kernel<<<E / 256, 256, 0, stream>>>(eidx, cnt);
    scan_kernel<<<1, 1024, 0, stream>>>(cnt, off, cursor);
    fill_adj<<<E / 256, 256, 0, stream>>>(eidx, cursor, adj);
    degf_kernel<<<V / 256, 256, 0, stream>>>(off, degf);

    // ---- weights -> bf16 transposed
    wtrans<<<(512 * 256 + 255) / 256, 256, 0, stream>>>(w0_1, w01t, 256, 512);
    wtrans<<<(512 * 256 + 255) / 256, 256, 0, stream>>>(w1_1, w11t, 256, 512);
    wtrans<<<(1024 * 512 + 255) / 256, 256, 0, stream>>>(w0_2, w02t, 512, 1024);
    wtrans<<<(1024 * 512 + 255) / 256, 256, 0, stream>>>(w1_2, w12t, 512, 1024);

    // ---- layer 0 (3 -> 256)
    gather0<<<V / 256, 256, 0, stream>>>(off, adj, verts, S0);
    l0_compute<<<V * 64 / 256, 256, 0, stream>>>(verts, S0, off, w0_0, b0_0, w1_0, b1_0, X1);
    hipMemsetAsync(stats, 0, 2048 * 4, stream);
    bn_stats<<<dim3(V / 256, 1), 256, 0, stream>>>(X1, stats, stats + 1024, 256);
    bn_finalize<<<1, 256, 0, stream>>>(stats, stats + 1024, g_0, be_0, scalev, shiftv);
    bn_apply<<<V * 256 / 4 / 256, 256, 0, stream>>>(X1, scalev, shiftv, 255);

    // ---- layer 1 (256 -> 512)
    gather_kernel<<<V, 256, 0, stream>>>(off, adj, X1, S, 256);
    gemm_mfma<<<dim3(4, V / 128), 256, 0, stream>>>(X1, S, w01t, w11t, b0_1, b1_1, degf,
                                                    X2, 256, 0, 512);
    hipMemsetAsync(stats, 0, 2048 * 4, stream);
    bn_stats<<<dim3(V / 256, 2), 256, 0, stream>>>(X2, stats, stats + 1024, 512);
    bn_finalize<<<2, 256, 0, stream>>>(stats, stats + 1024, g_1, be_1, scalev, shiftv);
    bn_apply<<<V * 512 / 4 / 256, 256, 0, stream>>>(X2, scalev, shiftv, 511);

    // ---- layer 2 (512 -> 1024), 4 column chunks of 256
    gather_kernel<<<V, 256, 0, stream>>>(off, adj, X2, S, 512);
    for (int cb = 0; cb < 1024; cb += 256) {
        gemm_mfma<<<dim3(2, V / 128), 256, 0, stream>>>(X2, S, w02t, w12t, b0_2, b1_2, degf,
                                                        Y2c, 512, cb, 256);
        hipMemsetAsync(stats, 0, 2048 * 4, stream);
        bn_stats<<<dim3(V / 256, 1), 256, 0, stream>>>(Y2c, stats, stats + 1024, 256);
        bn_finalize<<<1, 256, 0, stream>>>(stats, stats + 1024, g_2 + cb, be_2 + cb, scalev, shiftv);
        bn_apply<<<V * 256 / 4 / 256, 256, 0, stream>>>(Y2c, scalev, shiftv, 255);
        pool_kernel<<<dim3(64, 1), 256, 0, stream>>>(Y2c, pooled, 256, cb);
    }

    // ---- heads
    head_kernel<<<64, 128, 0, stream>>>(pooled, fc1w, fc1b, sw, sb, mw, mb, fw, fb, aw, ab, out);
}

// Round 8
// 853.307 us; speedup vs baseline: 3.6078x; 1.5971x over previous
//
#include <hip/hip_runtime.h>

#define V_N 65536
#define E_N 196608

typedef unsigned short u16;
typedef __attribute__((ext_vector_type(8))) short bf16x8;
typedef __attribute__((ext_vector_type(4))) float f32x4;

__device__ __forceinline__ float bf2f(u16 u) { return __uint_as_float(((unsigned)u) << 16); }
__device__ __forceinline__ u16 f2bf(float f) {
    unsigned x = __float_as_uint(f);
    return (u16)((x + 0x7fffu + ((x >> 16) & 1u)) >> 16);
}

__device__ __forceinline__ void gload_lds16(const u16* g, u16* l) {
    __builtin_amdgcn_global_load_lds(
        (const __attribute__((address_space(1))) unsigned int*)g,
        (__attribute__((address_space(3))) unsigned int*)l, 16, 0, 0);
}

// ---- edge dtype detect
__global__ void detect_kernel(const unsigned long long* e64, int* eflag) {
    __shared__ int bad;
    if (threadIdx.x == 0) bad = 0;
    __syncthreads();
    if (e64[threadIdx.x] >= (unsigned long long)V_N) atomicOr(&bad, 1);
    __syncthreads();
    if (threadIdx.x == 0) eflag[0] = bad ? 0 : 1;
}

__global__ __launch_bounds__(256) void convert_edges(const void* eraw, const int* eflag, int* eidx) {
    int k = blockIdx.x * 256 + threadIdx.x;
    int v;
    if (eflag[0]) v = (int)((const long long*)eraw)[k];
    else          v = ((const int*)eraw)[k];
    eidx[k] = v;
}

// ---- CSR build
__global__ __launch_bounds__(256) void cnt_kernel(const int* __restrict__ eidx, int* __restrict__ cnt) {
    int e = blockIdx.x * 256 + threadIdx.x;
    atomicAdd(&cnt[eidx[2 * e]], 1);
    atomicAdd(&cnt[eidx[2 * e + 1]], 1);
}

__global__ void scan_kernel(const int* __restrict__ cnt, int* __restrict__ off, int* __restrict__ cursor) {
    __shared__ int partial[1024];
    int t = threadIdx.x;
    int base = t * 64;
    int s = 0;
    #pragma unroll 4
    for (int k = 0; k < 64; ++k) s += cnt[base + k];
    partial[t] = s;
    __syncthreads();
    for (int d = 1; d < 1024; d <<= 1) {
        int v = (t >= d) ? partial[t - d] : 0;
        __syncthreads();
        partial[t] += v;
        __syncthreads();
    }
    int run = (t == 0) ? 0 : partial[t - 1];
    for (int k = 0; k < 64; ++k) {
        int idx = base + k;
        off[idx] = run; cursor[idx] = run;
        run += cnt[idx];
    }
    if (t == 1023) off[V_N] = run;
}

__global__ __launch_bounds__(256) void fill_adj(const int* __restrict__ eidx, int* __restrict__ cursor,
                                                int* __restrict__ adj) {
    int e = blockIdx.x * 256 + threadIdx.x;
    int i = eidx[2 * e], j = eidx[2 * e + 1];
    adj[atomicAdd(&cursor[i], 1)] = j;
    adj[atomicAdd(&cursor[j], 1)] = i;
}

__global__ __launch_bounds__(256) void degf_kernel(const int* __restrict__ off, float* __restrict__ deg) {
    int i = blockIdx.x * 256 + threadIdx.x;
    deg[i] = (float)(off[i + 1] - off[i]);
}

// ---- weight convert+transpose: w [K][N] fp32 -> wt [N][K] bf16
__global__ __launch_bounds__(256) void wtrans(const float* __restrict__ w, u16* __restrict__ wt,
                                              int K, int N) {
    int gid = blockIdx.x * 256 + threadIdx.x;
    if (gid >= N * K) return;
    int n = gid / K, k = gid % K;
    wt[gid] = f2bf(w[(size_t)k * N + n]);
}

// ---- layer-0 gather (din=3, fp32)
__global__ __launch_bounds__(256) void gather0(const int* __restrict__ off, const int* __restrict__ adj,
                                               const float* __restrict__ verts, float* __restrict__ S0) {
    int i = blockIdx.x * 256 + threadIdx.x;
    float s0 = 0.f, s1 = 0.f, s2 = 0.f;
    int o1 = off[i + 1];
    for (int o = off[i]; o < o1; ++o) {
        int j = adj[o];
        s0 += verts[3 * j]; s1 += verts[3 * j + 1]; s2 += verts[3 * j + 2];
    }
    S0[3 * i] = s0; S0[3 * i + 1] = s1; S0[3 * i + 2] = s2;
}

// ---- layer 0 dense (3 -> 256), bf16 out
__global__ __launch_bounds__(256) void l0_compute(
    const float* __restrict__ verts, const float* __restrict__ S0, const int* __restrict__ off,
    const float* __restrict__ w0, const float* __restrict__ b0,
    const float* __restrict__ w1, const float* __restrict__ b1, u16* __restrict__ Y) {
    int gid = blockIdx.x * 256 + threadIdx.x;
    int r = gid >> 6;
    int c = (gid & 63) << 2;
    float x0 = verts[3 * r], x1 = verts[3 * r + 1], x2 = verts[3 * r + 2];
    float s0 = S0[3 * r], s1 = S0[3 * r + 1], s2 = S0[3 * r + 2];
    float d = (float)(off[r + 1] - off[r]);
    float4 A0 = *(const float4*)&w0[c], A1 = *(const float4*)&w0[256 + c], A2 = *(const float4*)&w0[512 + c];
    float4 C0 = *(const float4*)&w1[c], C1 = *(const float4*)&w1[256 + c], C2 = *(const float4*)&w1[512 + c];
    float4 B0 = *(const float4*)&b0[c], B1 = *(const float4*)&b1[c];
    float4 y;
    y.x = B0.x + d * B1.x + x0 * A0.x + x1 * A1.x + x2 * A2.x + s0 * C0.x + s1 * C1.x + s2 * C2.x;
    y.y = B0.y + d * B1.y + x0 * A0.y + x1 * A1.y + x2 * A2.y + s0 * C0.y + s1 * C1.y + s2 * C2.y;
    y.z = B0.z + d * B1.z + x0 * A0.z + x1 * A1.z + x2 * A2.z + s0 * C0.z + s1 * C1.z + s2 * C2.z;
    y.w = B0.w + d * B1.w + x0 * A0.w + x1 * A1.w + x2 * A2.w + s0 * C0.w + s1 * C1.w + s2 * C2.w;
    ushort4 o; o.x = f2bf(y.x); o.y = f2bf(y.y); o.z = f2bf(y.z); o.w = f2bf(y.w);
    *(ushort4*)&Y[(size_t)r * 256 + c] = o;
}

// ---- vectorized neighbor gather: wave per vertex, lane holds CPL cols in fp32 regs
template <int CPL>
__global__ __launch_bounds__(256) void gather_vec(
    const int* __restrict__ off, const int* __restrict__ adj,
    const u16* __restrict__ X, u16* __restrict__ S, int K) {
    int vtx = blockIdx.x * 4 + (threadIdx.x >> 6);
    int lane = threadIdx.x & 63;
    int c0 = lane * CPL;
    int o0 = off[vtx], o1 = off[vtx + 1];
    float acc[CPL] = {};
    for (int o = o0; o < o1; ++o) {
        const u16* p = X + (size_t)adj[o] * K + c0;
        if constexpr (CPL == 8) {
            bf16x8 v = *(const bf16x8*)p;
            #pragma unroll
            for (int k = 0; k < 8; ++k) acc[k] += bf2f((u16)v[k]);
        } else {
            ushort4 v = *(const ushort4*)p;
            acc[0] += bf2f(v.x); acc[1] += bf2f(v.y);
            acc[2] += bf2f(v.z); acc[3] += bf2f(v.w);
        }
    }
    u16 ov[CPL];
    #pragma unroll
    for (int k = 0; k < CPL; ++k) ov[k] = f2bf(acc[k]);
    if constexpr (CPL == 8) *(bf16x8*)(S + (size_t)vtx * K + c0) = *(bf16x8*)ov;
    else                    *(ushort4*)(S + (size_t)vtx * K + c0) = *(ushort4*)ov;
}

// ---- MFMA GEMM + fused per-column BN-stats accumulation
__global__ __launch_bounds__(256) void gemm_mfma(
    const u16* __restrict__ X, const u16* __restrict__ S,
    const u16* __restrict__ W0t, const u16* __restrict__ W1t,
    const float* __restrict__ b0, const float* __restrict__ b1,
    const float* __restrict__ deg,
    u16* __restrict__ Y, float* __restrict__ sums, float* __restrict__ sqs,
    int K, int colbase, int ldY)
{
    __shared__ u16 As[128 * 64];
    __shared__ u16 Bs[128 * 64];
    const int tid = threadIdx.x;
    const int wid = tid >> 6, lane = tid & 63;
    const int brow = blockIdx.y * 128;
    const int bcol = blockIdx.x * 128;
    const int wm = wid >> 1, wn = wid & 1;

    const int sr = lane >> 3;
    const int sg = lane & 7;
    const int sgl = sg ^ sr;
    const int fr = lane & 15;
    const int fg = lane >> 4;

    f32x4 acc[4][4] = {};

    for (int ph = 0; ph < 2; ++ph) {
        const u16* Ap = ph ? S : X;
        const u16* Bp = (ph ? W1t : W0t) + (size_t)colbase * K;
        const u16* asrc = Ap + (size_t)(brow + wid * 32 + sr) * K + sgl * 8;
        const u16* bsrc = Bp + (size_t)(bcol + wid * 32 + sr) * K + sgl * 8;
        u16* adst = As + wid * 32 * 64;
        u16* bdst = Bs + wid * 32 * 64;

        for (int k0 = 0; k0 < K; k0 += 64) {
            if (ph | k0) __syncthreads();
            #pragma unroll
            for (int i = 0; i < 4; ++i) {
                gload_lds16(asrc + (size_t)i * 8 * K + k0, adst + i * 8 * 64);
                gload_lds16(bsrc + (size_t)i * 8 * K + k0, bdst + i * 8 * 64);
            }
            __syncthreads();

            bf16x8 afrag[4][2], bfrag[4][2];
            #pragma unroll
            for (int f = 0; f < 4; ++f) {
                int ar = wm * 64 + f * 16 + fr;
                int br = wn * 64 + f * 16 + fr;
                #pragma unroll
                for (int ks = 0; ks < 2; ++ks) {
                    int gp = (ks * 4 + fg) ^ (fr & 7);
                    afrag[f][ks] = *(const bf16x8*)(As + ar * 64 + gp * 8);
                    bfrag[f][ks] = *(const bf16x8*)(Bs + br * 64 + gp * 8);
                }
            }
            #pragma unroll
            for (int ks = 0; ks < 2; ++ks)
                #pragma unroll
                for (int fm = 0; fm < 4; ++fm)
                    #pragma unroll
                    for (int fn = 0; fn < 4; ++fn)
                        acc[fm][fn] = __builtin_amdgcn_mfma_f32_16x16x32_bf16(
                            afrag[fm][ks], bfrag[fn][ks], acc[fm][fn], 0, 0, 0);
        }
    }

    // epilogue: store + per-column sum/sumsq (C/D: col = lane&15, row = (lane>>4)*4 + reg)
    #pragma unroll
    for (int fn = 0; fn < 4; ++fn) {
        int col = bcol + wn * 64 + fn * 16 + fr;      // chunk-local column
        float B0 = b0[colbase + col];
        float B1 = b1[colbase + col];
        float s = 0.f, q = 0.f;
        #pragma unroll
        for (int fm = 0; fm < 4; ++fm) {
            #pragma unroll
            for (int r = 0; r < 4; ++r) {
                int row = brow + wm * 64 + fm * 16 + fg * 4 + r;
                float v = acc[fm][fn][r] + B0 + deg[row] * B1;
                Y[(size_t)row * ldY + col] = f2bf(v);
                s += v; q += v * v;
            }
        }
        s += __shfl_xor(s, 16); s += __shfl_xor(s, 32);
        q += __shfl_xor(q, 16); q += __shfl_xor(q, 32);
        if (lane < 16) {
            atomicAdd(&sums[col], s);
            atomicAdd(&sqs[col], q);
        }
    }
}

// ---- per-channel sum / sumsq (layer-0 only)
__global__ __launch_bounds__(256) void bn_stats(
    const u16* __restrict__ Y, float* __restrict__ sums, float* __restrict__ sqs, int N) {
    int c = blockIdx.y * 256 + threadIdx.x;
    int r0 = blockIdx.x * 256;
    float s = 0.f, q = 0.f;
    for (int r = r0; r < r0 + 256; ++r) {
        float v = bf2f(Y[(size_t)r * N + c]);
        s += v; q += v * v;
    }
    atomicAdd(&sums[c], s);
    atomicAdd(&sqs[c], q);
}

// ---- BN apply (finalize inline): Y = relu(scale*Y + shift), in place
__global__ __launch_bounds__(256) void bn_apply(
    u16* __restrict__ Y, const float* __restrict__ sums, const float* __restrict__ sqs,
    const float* __restrict__ g, const float* __restrict__ be, int Nmask) {
    int gid = blockIdx.x * 256 + threadIdx.x;
    int c = (gid << 2) & Nmask;
    float4 s4 = *(const float4*)&sums[c];
    float4 q4 = *(const float4*)&sqs[c];
    float4 g4 = *(const float4*)&g[c];
    float4 e4 = *(const float4*)&be[c];
    float sc[4], sh[4];
    float mus[4] = {s4.x, s4.y, s4.z, s4.w}, qs[4] = {q4.x, q4.y, q4.z, q4.w};
    float gs[4] = {g4.x, g4.y, g4.z, g4.w}, es[4] = {e4.x, e4.y, e4.z, e4.w};
    #pragma unroll
    for (int k = 0; k < 4; ++k) {
        float mu = mus[k] * (1.f / V_N);
        float var = qs[k] * (1.f / V_N) - mu * mu;
        sc[k] = gs[k] * rsqrtf(var + 1e-5f);
        sh[k] = es[k] - mu * sc[k];
    }
    ushort4 v = *(ushort4*)&Y[(size_t)gid * 4];
    ushort4 o;
    o.x = f2bf(fmaxf(bf2f(v.x) * sc[0] + sh[0], 0.f));
    o.y = f2bf(fmaxf(bf2f(v.y) * sc[1] + sh[1], 0.f));
    o.z = f2bf(fmaxf(bf2f(v.z) * sc[2] + sh[2], 0.f));
    o.w = f2bf(fmaxf(bf2f(v.w) * sc[3] + sh[3], 0.f));
    *(ushort4*)&Y[(size_t)gid * 4] = o;
}

// ---- layer-2 fused: finalize + affine + relu + segment-sum (no writeback of Y)
__global__ __launch_bounds__(256) void bn_pool(
    const u16* __restrict__ Y, const float* __restrict__ sums, const float* __restrict__ sqs,
    const float* __restrict__ g, const float* __restrict__ be, float* __restrict__ pooledB) {
    int m = blockIdx.x, qr = blockIdx.y;
    int c = threadIdx.x;
    float mu = sums[c] * (1.f / V_N);
    float var = sqs[c] * (1.f / V_N) - mu * mu;
    float sc = g[c] * rsqrtf(var + 1e-5f);
    float sh = be[c] - mu * sc;
    const u16* p = Y + (size_t)(m * 1024 + qr * 256) * 256 + c;
    float s = 0.f;
    for (int r = 0; r < 256; ++r)
        s += fmaxf(bf2f(p[(size_t)r * 256]) * sc + sh, 0.f);
    atomicAdd(&pooledB[m * 1024 + c], s);
}

// ---- fc1 + relu + 4 heads (pooled holds raw sums; scale by 1/1024 here)
__global__ __launch_bounds__(128) void head_kernel(
    const float* __restrict__ pooled,
    const float* __restrict__ fc1w, const float* __restrict__ fc1b,
    const float* __restrict__ sw, const float* __restrict__ sb,
    const float* __restrict__ mw, const float* __restrict__ mb,
    const float* __restrict__ fw, const float* __restrict__ fb,
    const float* __restrict__ aw, const float* __restrict__ ab,
    float* __restrict__ out) {
    __shared__ float xs[1024];
    __shared__ float hs[128];
    int m = blockIdx.x, t = threadIdx.x;
    for (int k = t; k < 1024; k += 128) xs[k] = pooled[m * 1024 + k] * (1.f / 1024.f);
    __syncthreads();
    float acc = fc1b[t];
    for (int k = 0; k < 1024; ++k) acc += xs[k] * fc1w[k * 128 + t];
    hs[t] = fmaxf(acc, 0.f);
    __syncthreads();
    if (t < 14) {
        const float* w; const float* bv; int cdim; int o; int base;
        if (t < 3)      { w = sw; bv = sb; cdim = 3; o = t;     base = 0;   }
        else if (t < 5) { w = mw; bv = mb; cdim = 2; o = t - 3; base = 192; }
        else if (t < 9) { w = fw; bv = fb; cdim = 4; o = t - 5; base = 320; }
        else            { w = aw; bv = ab; cdim = 5; o = t - 9; base = 576; }
        float a = bv[o];
        for (int k = 0; k < 128; ++k) a += hs[k] * w[k * cdim + o];
        out[base + m * cdim + o] = a;
    }
}

extern "C" void kernel_launch(void* const* d_in, const int* in_sizes, int n_in,
                              void* d_out, int out_size, void* d_ws, size_t ws_size,
                              hipStream_t stream)
{
    const float* verts = (const float*)d_in[0];
    const void*  eraw  = d_in[1];
    const float* w0_0 = (const float*)d_in[3];  const float* b0_0 = (const float*)d_in[4];
    const float* w1_0 = (const float*)d_in[5];  const float* b1_0 = (const float*)d_in[6];
    const float* g_0  = (const float*)d_in[7];  const float* be_0 = (const float*)d_in[8];
    const float* w0_1 = (const float*)d_in[9];  const float* b0_1 = (const float*)d_in[10];
    const float* w1_1 = (const float*)d_in[11]; const float* b1_1 = (const float*)d_in[12];
    const float* g_1  = (const float*)d_in[13]; const float* be_1 = (const float*)d_in[14];
    const float* w0_2 = (const float*)d_in[15]; const float* b0_2 = (const float*)d_in[16];
    const float* w1_2 = (const float*)d_in[17]; const float* b1_2 = (const float*)d_in[18];
    const float* g_2  = (const float*)d_in[19]; const float* be_2 = (const float*)d_in[20];
    const float* fc1w = (const float*)d_in[21]; const float* fc1b = (const float*)d_in[22];
    const float* sw = (const float*)d_in[23]; const float* sb = (const float*)d_in[24];
    const float* mw = (const float*)d_in[25]; const float* mb = (const float*)d_in[26];
    const float* fw = (const float*)d_in[27]; const float* fb = (const float*)d_in[28];
    const float* aw = (const float*)d_in[29]; const float* ab = (const float*)d_in[30];
    float* out = (float*)d_out;

    const size_t V = V_N, E = E_N;

    // ---- workspace layout
    char* p = (char*)d_ws;
    auto alloc = [&](size_t bytes) { void* r = (void*)p; p += (bytes + 255) & ~(size_t)255; return r; };
    int*   eidx   = (int*)  alloc(2 * E * 4);
    int*   eflag  = (int*)  alloc(64);
    int*   cnt    = (int*)  alloc(V * 4);
    int*   off    = (int*)  alloc((V + 1) * 4);
    int*   cursor = (int*)  alloc(V * 4);
    int*   adj    = (int*)  alloc(2 * E * 4);
    float* degf   = (float*)alloc(V * 4);
    float* S0     = (float*)alloc(V * 3 * 4);
    float* stats  = (float*)alloc(2048 * 4);
    float* pooled = (float*)alloc(65536 * 4);
    u16*   w01t   = (u16*)  alloc(512 * 256 * 2);
    u16*   w11t   = (u16*)  alloc(512 * 256 * 2);
    u16*   w02t   = (u16*)  alloc(1024 * 512 * 2);
    u16*   w12t   = (u16*)  alloc(1024 * 512 * 2);
    u16*   X1     = (u16*)  alloc(V * 256 * 2);
    u16*   X2     = (u16*)  alloc(V * 512 * 2);
    u16*   S      = (u16*)  alloc(V * 512 * 2);
    u16*   Y2c    = X1;                     // alias: X1 dead once L2 GEMM starts
    size_t needed = (size_t)(p - (char*)d_ws);

    if (ws_size < needed) {
        hipMemsetAsync(d_out, 0, (size_t)out_size * 4, stream);
        return;
    }

    // ---- edges -> int32, CSR, deg
    detect_kernel<<<1, 256, 0, stream>>>((const unsigned long long*)eraw, eflag);
    convert_edges<<<2 * E / 256, 256, 0, stream>>>(eraw, eflag, eidx);
    hipMemsetAsync(cnt, 0, V * 4, stream);
    cnt_kernel<<<E / 256, 256, 0, stream>>>(eidx, cnt);
    scan_kernel<<<1, 1024, 0, stream>>>(cnt, off, cursor);
    fill_adj<<<E / 256, 256, 0, stream>>>(eidx, cursor, adj);
    degf_kernel<<<V / 256, 256, 0, stream>>>(off, degf);

    // ---- weights -> bf16 transposed
    wtrans<<<(512 * 256 + 255) / 256, 256, 0, stream>>>(w0_1, w01t, 256, 512);
    wtrans<<<(512 * 256 + 255) / 256, 256, 0, stream>>>(w1_1, w11t, 256, 512);
    wtrans<<<(1024 * 512 + 255) / 256, 256, 0, stream>>>(w0_2, w02t, 512, 1024);
    wtrans<<<(1024 * 512 + 255) / 256, 256, 0, stream>>>(w1_2, w12t, 512, 1024);

    // ---- layer 0 (3 -> 256)
    gather0<<<V / 256, 256, 0, stream>>>(off, adj, verts, S0);
    l0_compute<<<V * 64 / 256, 256, 0, stream>>>(verts, S0, off, w0_0, b0_0, w1_0, b1_0, X1);
    hipMemsetAsync(stats, 0, 2048 * 4, stream);
    bn_stats<<<dim3(V / 256, 1), 256, 0, stream>>>(X1, stats, stats + 1024, 256);
    bn_apply<<<V * 256 / 4 / 256, 256, 0, stream>>>(X1, stats, stats + 1024, g_0, be_0, 255);

    // ---- layer 1 (256 -> 512)
    gather_vec<4><<<V / 4, 256, 0, stream>>>(off, adj, X1, S, 256);
    hipMemsetAsync(stats, 0, 2048 * 4, stream);
    gemm_mfma<<<dim3(4, V / 128), 256, 0, stream>>>(X1, S, w01t, w11t, b0_1, b1_1, degf,
                                                    X2, stats, stats + 1024, 256, 0, 512);
    bn_apply<<<V * 512 / 4 / 256, 256, 0, stream>>>(X2, stats, stats + 1024, g_1, be_1, 511);

    // ---- layer 2 (512 -> 1024), 4 column chunks of 256
    gather_vec<8><<<V / 4, 256, 0, stream>>>(off, adj, X2, S, 512);
    hipMemsetAsync(pooled, 0, 65536 * 4, stream);
    for (int cb = 0; cb < 1024; cb += 256) {
        hipMemsetAsync(stats, 0, 2048 * 4, stream);
        gemm_mfma<<<dim3(2, V / 128), 256, 0, stream>>>(X2, S, w02t, w12t, b0_2, b1_2, degf,
                                                        Y2c, stats, stats + 1024, 512, cb, 256);
        bn_pool<<<dim3(64, 4), 256, 0, stream>>>(Y2c, stats, stats + 1024, g_2 + cb, be_2 + cb,
                                                 pooled + cb);
    }

    // ---- heads
    head_kernel<<<64, 128, 0, stream>>>(pooled, fc1w, fc1b, sw, sb, mw, mb, fw, fb, aw, ab, out);
}